// Round 3
// baseline (558.410 us; speedup 1.0000x reference)
//
#include <hip/hip_runtime.h>
#include <hip/hip_bf16.h>
#include <math.h>

#define B_    2
#define S_    2048
#define DM    512
#define H_    8
#define PROJ  1544
#define NPAD1 1664        // 13*128
#define CHK   64
#define NC    32
#define BS_   4096
#define BH    16
#define NBLK  512

typedef __attribute__((ext_vector_type(8))) short shortx8;
typedef __attribute__((ext_vector_type(4))) short shortx4;
typedef __attribute__((ext_vector_type(4))) float floatx4;

#define GCAST(p) ((const __attribute__((address_space(1))) void*)(p))
#define LCAST(p) ((__attribute__((address_space(3))) void*)(p))

__device__ inline short f2bf(float f) {
    __hip_bfloat16 h = __float2bfloat16(f);
    return *(short*)&h;
}
__device__ inline float bf2f(short s) {
    __hip_bfloat16 h = *(__hip_bfloat16*)&s;
    return __bfloat162float(h);
}
// Read 8 contiguous bf16 (k mult of 8) from a 64-k-wide tile whose 16B groups
// are XOR-swizzled by row: element (row,k) lives at group (k>>3)^(row&7).
__device__ inline shortx8 read8(const short* buf, int row, int k) {
    return *(const shortx8*)&buf[row * 64 + ((((k >> 3) ^ (row & 7))) << 3)];
}

// Hand-rolled inlined grid barrier (avoids __ockl_grid_sync call ABI which
// collapsed VGPR allocation to 68 and spilled everything in R2).
// Counters zeroed by hipMemsetAsync at graph head; one slot per sync point.
__device__ __forceinline__ void gridbar(unsigned* cnt, int idx) {
    __syncthreads();
    if (threadIdx.x == 0) {
        __threadfence();   // release: make this block's writes device-visible
        __hip_atomic_fetch_add(&cnt[idx * 32], 1u, __ATOMIC_ACQ_REL,
                               __HIP_MEMORY_SCOPE_AGENT);
        while (__hip_atomic_load(&cnt[idx * 32], __ATOMIC_ACQUIRE,
                                 __HIP_MEMORY_SCOPE_AGENT) < (unsigned)NBLK)
            __builtin_amdgcn_s_sleep(2);
    }
    __syncthreads();
    __threadfence();       // acquire: discard stale L1 lines before reads
}

#define E1 ((size_t)BS_ * DM)
#define E2 ((size_t)NPAD1 * DM)
#define E3 ((size_t)DM * DM)

// ===========================================================================
// MEGA: one persistent cooperative kernel, 512 blocks x 256 threads
// (2 blocks/CU; LDS 50432B; VGPR capped 256 by __launch_bounds__(256,2)).
// Phases: P0 convert | P1 gemm1 128x128 (416 tiles) | P2 chunk_kv (512) |
//         P3 attn w/ direct prefix sum (512) | P4 gemm2 64x64 (512)
// 4 inlined grid barriers; scan phase removed (attn sums kvbuf directly).
// ===========================================================================
__global__ __launch_bounds__(256, 2) void mega(
        const float* __restrict__ x,  const float* __restrict__ w1,
        const float* __restrict__ w2, const float* __restrict__ bias1,
        const float* __restrict__ bias2,
        short* __restrict__ xb, short* __restrict__ w1b, short* __restrict__ w2b,
        short* __restrict__ qb, short* __restrict__ kb, short* __restrict__ kTb,
        short* __restrict__ vTb, float* __restrict__ gateb,
        float* __restrict__ kvbuf, short* __restrict__ ctxb,
        float* __restrict__ out, unsigned* __restrict__ barcnt) {
    __shared__ __align__(16) char smem[50432];
    const int blk  = blockIdx.x;
    const int tid  = threadIdx.x;
    const int wave = tid >> 6, lane = tid & 63;
    const int lrow = lane >> 3, lgrp = lane & 7;
    const int lm = lane & 15, q = lane >> 4;

    // ---------------- P0: fp32->bf16 convert (x, W1 zero-padded, W2) -------
    for (size_t c = (size_t)blk * 256 + tid; c < (E1 + E2 + E3) / 8; c += NBLK * 256) {
        size_t e = c * 8;
        const float* src;
        short* dst;
        bool zero = false;
        if (e < E1) { src = x + e; dst = xb + e; }
        else if (e < E1 + E2) {
            size_t o = e - E1;
            dst = w1b + o;
            size_t row = o >> 9;
            if (row < PROJ) src = w1 + o; else { src = w1; zero = true; }
        } else {
            size_t o = e - E1 - E2;
            src = w2 + o; dst = w2b + o;
        }
        short o8[8];
        if (zero) {
#pragma unroll
            for (int i = 0; i < 8; i++) o8[i] = 0;
        } else {
            float4 f0 = *(const float4*)src;
            float4 f1 = *(const float4*)(src + 4);
            o8[0] = f2bf(f0.x); o8[1] = f2bf(f0.y); o8[2] = f2bf(f0.z); o8[3] = f2bf(f0.w);
            o8[4] = f2bf(f1.x); o8[5] = f2bf(f1.y); o8[6] = f2bf(f1.z); o8[7] = f2bf(f1.w);
        }
        *(shortx8*)dst = *(shortx8*)o8;
    }
    gridbar(barcnt, 0);

    // ---------------- P1: gemm1 128x128 BK=64 + scatter epilogue -----------
    if (blk < 416) {
        short* As = (short*)smem;             // 128*64
        short* Bs = (short*)(smem + 16384);   // 128*64
        const int K  = DM;
        const int bx = blk % 13, by = blk / 13;
        const int m0 = by * 128, n0 = bx * 128;
        const int swz = ((lane & 7) ^ lrow) << 3;
        const int wr = (wave >> 1) * 64, wc = (wave & 1) * 64;
        floatx4 acc[4][4] = {};

        const short* gA[4];
        const short* gB[4];
#pragma unroll
        for (int g = 0; g < 4; g++)
            gA[g] = xb + (size_t)(m0 + g * 32 + wave * 8 + lrow) * K + swz;
#pragma unroll
        for (int h = 0; h < 4; h++)
            gB[h] = w1b + (size_t)(n0 + h * 32 + wave * 8 + lrow) * K + swz;

        for (int k0 = 0; k0 < K; k0 += 64) {
#pragma unroll
            for (int g = 0; g < 4; g++)
                __builtin_amdgcn_global_load_lds(GCAST(gA[g] + k0), LCAST(&As[(g * 32 + wave * 8) * 64]), 16, 0, 0);
#pragma unroll
            for (int h = 0; h < 4; h++)
                __builtin_amdgcn_global_load_lds(GCAST(gB[h] + k0), LCAST(&Bs[(h * 32 + wave * 8) * 64]), 16, 0, 0);
            __syncthreads();
            shortx8 af[2][4], bw[2][4];
#pragma unroll
            for (int ks = 0; ks < 2; ks++) {
#pragma unroll
                for (int i = 0; i < 4; i++) af[ks][i] = read8(As, wr + i * 16 + lm, ks * 32 + q * 8);
#pragma unroll
                for (int j = 0; j < 4; j++) bw[ks][j] = read8(Bs, wc + j * 16 + lm, ks * 32 + q * 8);
            }
#pragma unroll
            for (int ks = 0; ks < 2; ks++)
#pragma unroll
                for (int i = 0; i < 4; i++)
#pragma unroll
                    for (int j = 0; j < 4; j++)
                        acc[i][j] = __builtin_amdgcn_mfma_f32_16x16x32_bf16(af[ks][i], bw[ks][j], acc[i][j], 0, 0, 0);
            __syncthreads();
        }

        const int bIdx = m0 >> 11;
        const int bh0  = bIdx * H_;
#pragma unroll
        for (int i = 0; i < 4; i++) {
            int s0 = (m0 & (S_ - 1)) + wr + i * 16 + q * 4;
#pragma unroll
            for (int j = 0; j < 4; j++) {
                int col = n0 + wc + j * 16 + lm;
                float bv = (col < PROJ) ? bias1[col] : 0.f;
                float vals[4];
#pragma unroll
                for (int r = 0; r < 4; r++) vals[r] = acc[i][j][r] + bv;
                if (col < 512) {                       // v -> vT[bh][v][s]
                    int h = col >> 6, vd = col & 63;
                    short tmp[4];
#pragma unroll
                    for (int r = 0; r < 4; r++) tmp[r] = f2bf(vals[r]);
                    *(shortx4*)&vTb[((size_t)(bh0 + h) * 64 + vd) * S_ + s0] = *(shortx4*)tmp;
                } else if (col < 1024) {               // q -> q[bh][s][d]
                    int h = (col >> 6) - 8, d = col & 63;
                    size_t rb = ((size_t)(bh0 + h) * S_ + s0) * 64 + d;
#pragma unroll
                    for (int r = 0; r < 4; r++) qb[rb + (size_t)r * 64] = f2bf(vals[r]);
                } else if (col < 1536) {               // k -> k[bh][t][d], kT[bh][d][t]
                    int h = (col >> 6) - 16, d = col & 63;
                    size_t rb = ((size_t)(bh0 + h) * S_ + s0) * 64 + d;
                    short tmp[4];
#pragma unroll
                    for (int r = 0; r < 4; r++) { tmp[r] = f2bf(vals[r]); kb[rb + (size_t)r * 64] = tmp[r]; }
                    *(shortx4*)&kTb[((size_t)(bh0 + h) * 64 + d) * S_ + s0] = *(shortx4*)tmp;
                } else if (col < PROJ) {               // n -> gate[bh][s]
                    int h = col - 1536;
                    float g[4];
#pragma unroll
                    for (int r = 0; r < 4; r++) g[r] = __expf(-__expf(vals[r]));
                    *(float4*)&gateb[(size_t)(bh0 + h) * S_ + s0] = make_float4(g[0], g[1], g[2], g[3]);
                }
            }
        }
    }
    gridbar(barcnt, 1);

    // ---------------- P2: per-chunk state U[v][d] via MFMA ------------------
    {
        short* VT = (short*)smem;             // 64*64
        short* KT = (short*)(smem + 8192);    // 64*64
        const int c = blk & (NC - 1), bh = blk >> 5;
        const int base = c * CHK;
#pragma unroll
        for (int half = 0; half < 2; half++) {
            int v0 = wave * 8 + half * 32;
            int row = v0 + lrow;
            int gcol = ((lgrp ^ (row & 7)) << 3);
            __builtin_amdgcn_global_load_lds(GCAST(vTb + ((size_t)(bh * 64 + row)) * S_ + base + gcol),
                                             LCAST(&VT[v0 * 64]), 16, 0, 0);
            __builtin_amdgcn_global_load_lds(GCAST(kTb + ((size_t)(bh * 64 + row)) * S_ + base + gcol),
                                             LCAST(&KT[v0 * 64]), 16, 0, 0);
        }
        __syncthreads();
        const int wr = (wave >> 1) * 32, wc = (wave & 1) * 32;
        floatx4 acc[2][2] = {};
#pragma unroll
        for (int ks = 0; ks < 2; ks++) {
            shortx8 a[2], b2[2];
#pragma unroll
            for (int i = 0; i < 2; i++) a[i]  = read8(VT, wr + i * 16 + lm, ks * 32 + q * 8);
#pragma unroll
            for (int j = 0; j < 2; j++) b2[j] = read8(KT, wc + j * 16 + lm, ks * 32 + q * 8);
#pragma unroll
            for (int i = 0; i < 2; i++)
#pragma unroll
                for (int j = 0; j < 2; j++)
                    acc[i][j] = __builtin_amdgcn_mfma_f32_16x16x32_bf16(a[i], b2[j], acc[i][j], 0, 0, 0);
        }
        float* outp = kvbuf + ((size_t)blk << 12);
#pragma unroll
        for (int i = 0; i < 2; i++)
#pragma unroll
            for (int j = 0; j < 2; j++)
#pragma unroll
                for (int r = 0; r < 4; r++)
                    outp[(wr + i * 16 + q * 4 + r) * 64 + wc + j * 16 + lm] = acc[i][j][r];
    }
    gridbar(barcnt, 2);

    // ---------------- P3: attention chunk, prefix summed from kvbuf ---------
    {
        short* Qs  = (short*)smem;            // 8K
        short* Ks  = (short*)(smem + 8192);   // 8K
        short* VTs = (short*)(smem + 16384);  // 8K
        short* Phi = (short*)(smem + 24576);  // 8K
        short* Plo = (short*)(smem + 32768);  // 8K
        short* Sb  = (short*)(smem + 40960);  // 64*72*2 = 9216
        float* gs  = (float*)(smem + 50176);  // 256B
        const int bh = blk & (BH - 1);
        const int c  = (NC - 1) - (blk >> 4);
        const int base = c * CHK;

#pragma unroll
        for (int half = 0; half < 2; half++) {
            int v0 = wave * 8 + half * 32;
            int row = v0 + lrow;
            int gcol = ((lgrp ^ (row & 7)) << 3);
            __builtin_amdgcn_global_load_lds(GCAST(qb + ((size_t)bh * S_ + base + row) * 64 + gcol),
                                             LCAST(&Qs[v0 * 64]), 16, 0, 0);
            __builtin_amdgcn_global_load_lds(GCAST(kb + ((size_t)bh * S_ + base + row) * 64 + gcol),
                                             LCAST(&Ks[v0 * 64]), 16, 0, 0);
            __builtin_amdgcn_global_load_lds(GCAST(vTb + ((size_t)(bh * 64 + row)) * S_ + base + gcol),
                                             LCAST(&VTs[v0 * 64]), 16, 0, 0);
        }

        // Exclusive prefix over preceding chunk states, straight from kvbuf
        // (L2/L3-resident; <=31 states x 16 indep loads/thread).
        float pacc[16];
#pragma unroll
        for (int it = 0; it < 16; it++) pacc[it] = 0.f;
        {
            const float* kvb = kvbuf + (((size_t)bh * NC) << 12) + tid;
            for (int cp = 0; cp < c; cp++) {
                const float* p = kvb + ((size_t)cp << 12);
#pragma unroll
                for (int it = 0; it < 16; it++) pacc[it] += p[it * 256];
            }
        }
#pragma unroll
        for (int it = 0; it < 16; it++) {
            int idx = it * 256 + tid;
            int v = idx >> 6, d = idx & 63;
            float f = pacc[it];
            short hi = f2bf(f);
            short lo = f2bf(f - bf2f(hi));
            int sw = v * 64 + (((d >> 3) ^ (v & 7)) << 3) + (d & 7);
            Phi[sw] = hi; Plo[sw] = lo;
        }
        if (tid < 64) gs[tid] = gateb[(size_t)bh * S_ + base + tid];
        __syncthreads();

        const int wr = (wave >> 1) * 32, wc = (wave & 1) * 32;

        // S = Q K^T, causal mask, -> Sb bf16
        floatx4 sacc[2][2] = {};
#pragma unroll
        for (int ks = 0; ks < 2; ks++) {
            shortx8 qa[2], kf[2];
#pragma unroll
            for (int i = 0; i < 2; i++) qa[i] = read8(Qs, wr + i * 16 + lm, ks * 32 + q * 8);
#pragma unroll
            for (int j = 0; j < 2; j++) kf[j] = read8(Ks, wc + j * 16 + lm, ks * 32 + q * 8);
#pragma unroll
            for (int i = 0; i < 2; i++)
#pragma unroll
                for (int j = 0; j < 2; j++)
                    sacc[i][j] = __builtin_amdgcn_mfma_f32_16x16x32_bf16(qa[i], kf[j], sacc[i][j], 0, 0, 0);
        }
#pragma unroll
        for (int i = 0; i < 2; i++)
#pragma unroll
            for (int j = 0; j < 2; j++)
#pragma unroll
                for (int r = 0; r < 4; r++) {
                    int s = wr + i * 16 + q * 4 + r;
                    int t = wc + j * 16 + lm;
                    Sb[s * 72 + t] = f2bf(t <= s ? sacc[i][j][r] : 0.f);
                }
        __syncthreads();

        // O = S.V + Q.(Phi+Plo)
        floatx4 oacc[2][2] = {};
#pragma unroll
        for (int ks = 0; ks < 2; ks++) {
            shortx8 sa[2], vb[2];
#pragma unroll
            for (int i = 0; i < 2; i++)
                sa[i] = *(const shortx8*)&Sb[(wr + i * 16 + lm) * 72 + ks * 32 + q * 8];
#pragma unroll
            for (int j = 0; j < 2; j++) vb[j] = read8(VTs, wc + j * 16 + lm, ks * 32 + q * 8);
#pragma unroll
            for (int i = 0; i < 2; i++)
#pragma unroll
                for (int j = 0; j < 2; j++)
                    oacc[i][j] = __builtin_amdgcn_mfma_f32_16x16x32_bf16(sa[i], vb[j], oacc[i][j], 0, 0, 0);
        }
#pragma unroll
        for (int ks = 0; ks < 2; ks++) {
            shortx8 qa[2], ph[2], pl[2];
#pragma unroll
            for (int i = 0; i < 2; i++) qa[i] = read8(Qs, wr + i * 16 + lm, ks * 32 + q * 8);
#pragma unroll
            for (int j = 0; j < 2; j++) {
                ph[j] = read8(Phi, wc + j * 16 + lm, ks * 32 + q * 8);
                pl[j] = read8(Plo, wc + j * 16 + lm, ks * 32 + q * 8);
            }
#pragma unroll
            for (int i = 0; i < 2; i++)
#pragma unroll
                for (int j = 0; j < 2; j++) {
                    oacc[i][j] = __builtin_amdgcn_mfma_f32_16x16x32_bf16(qa[i], ph[j], oacc[i][j], 0, 0, 0);
                    oacc[i][j] = __builtin_amdgcn_mfma_f32_16x16x32_bf16(qa[i], pl[j], oacc[i][j], 0, 0, 0);
                }
        }
        const size_t tok0 = (size_t)(bh >> 3) * S_ + base;
        const int h = bh & 7;
#pragma unroll
        for (int i = 0; i < 2; i++)
#pragma unroll
            for (int j = 0; j < 2; j++)
#pragma unroll
                for (int r = 0; r < 4; r++) {
                    int s = wr + i * 16 + q * 4 + r;
                    int v = wc + j * 16 + lm;
                    ctxb[(tok0 + s) * DM + h * 64 + v] = f2bf(gs[s] * oacc[i][j][r]);
                }
    }
    gridbar(barcnt, 3);

    // ---------------- P4: out-proj gemm, 64x64 tiles (512 exact) ------------
    {
        short* As = (short*)smem;             // 64*64
        short* Bs = (short*)(smem + 8192);    // 64*64
        const int m0 = (blk >> 3) * 64;
        const int n0 = (blk & 7) * 64;
        const int swz = (lgrp ^ lrow) << 3;
        const int wr = (wave >> 1) * 32, wc = (wave & 1) * 32;
        floatx4 acc[2][2] = {};
        for (int k0 = 0; k0 < DM; k0 += 64) {
#pragma unroll
            for (int half = 0; half < 2; half++) {
                int r0 = wave * 8 + half * 32;
                int row = r0 + lrow;
                __builtin_amdgcn_global_load_lds(GCAST(ctxb + (size_t)(m0 + row) * DM + k0 + swz),
                                                 LCAST(&As[r0 * 64]), 16, 0, 0);
                __builtin_amdgcn_global_load_lds(GCAST(w2b + (size_t)(n0 + row) * DM + k0 + swz),
                                                 LCAST(&Bs[r0 * 64]), 16, 0, 0);
            }
            __syncthreads();
            shortx8 a2[2][2], b2[2][2];
#pragma unroll
            for (int ks = 0; ks < 2; ks++) {
#pragma unroll
                for (int i = 0; i < 2; i++) a2[ks][i] = read8(As, wr + i * 16 + lm, ks * 32 + q * 8);
#pragma unroll
                for (int j = 0; j < 2; j++) b2[ks][j] = read8(Bs, wc + j * 16 + lm, ks * 32 + q * 8);
            }
#pragma unroll
            for (int ks = 0; ks < 2; ks++)
#pragma unroll
                for (int i = 0; i < 2; i++)
#pragma unroll
                    for (int j = 0; j < 2; j++)
                        acc[i][j] = __builtin_amdgcn_mfma_f32_16x16x32_bf16(a2[ks][i], b2[ks][j], acc[i][j], 0, 0, 0);
            __syncthreads();
        }
#pragma unroll
        for (int i = 0; i < 2; i++) {
            int rb = m0 + wr + i * 16 + q * 4;
#pragma unroll
            for (int j = 0; j < 2; j++) {
                int col = n0 + wc + j * 16 + lm;
                float bv = bias2[col];
#pragma unroll
                for (int r = 0; r < 4; r++)
                    out[(size_t)(rb + r) * DM + col] = acc[i][j][r] + bv;
            }
        }
    }
}

// ===========================================================================
// Fallback path: the verified 6-kernel pipeline (used only if cooperative
// launch is rejected by the runtime/graph capture).
// ===========================================================================
__global__ __launch_bounds__(256) void convert_all(const float* __restrict__ x,
                                                   const float* __restrict__ w1,
                                                   const float* __restrict__ w2,
                                                   short* __restrict__ xb,
                                                   short* __restrict__ w1b,
                                                   short* __restrict__ w2b) {
    size_t e = ((size_t)blockIdx.x * 256 + threadIdx.x) * 8;
    const float* src;
    short* dst;
    bool zero = false;
    if (e < E1) { src = x + e; dst = xb + e; }
    else if (e < E1 + E2) {
        size_t o = e - E1;
        dst = w1b + o;
        size_t row = o >> 9;
        if (row < PROJ) src = w1 + o; else { src = w1; zero = true; }
    } else if (e < E1 + E2 + E3) {
        size_t o = e - E1 - E2;
        src = w2 + o; dst = w2b + o;
    } else return;
    short out[8];
    if (zero) {
#pragma unroll
        for (int i = 0; i < 8; i++) out[i] = 0;
    } else {
        float4 f0 = *(const float4*)src;
        float4 f1 = *(const float4*)(src + 4);
        out[0] = f2bf(f0.x); out[1] = f2bf(f0.y); out[2] = f2bf(f0.z); out[3] = f2bf(f0.w);
        out[4] = f2bf(f1.x); out[5] = f2bf(f1.y); out[6] = f2bf(f1.z); out[7] = f2bf(f1.w);
    }
    *(shortx8*)dst = *(shortx8*)out;
}

__global__ __launch_bounds__(256) void gemm_mfma64(const short* __restrict__ A,
                                                   const short* __restrict__ Bw,
                                                   const float* __restrict__ bias,
                                                   float* __restrict__ C,
                                                   int N, int K) {
    __shared__ __align__(16) short As[64 * 64];
    __shared__ __align__(16) short Bs[128 * 64];
    const int tid  = threadIdx.x;
    const int wave = tid >> 6, lane = tid & 63;
    const int m0 = blockIdx.y * 64;
    const int n0 = blockIdx.x * 128;
    const int lrow = lane >> 3;
    const int swz  = ((lane & 7) ^ lrow) << 3;
    const int lm = lane & 15, q = lane >> 4;
    const int wc = wave * 32;
    floatx4 acc[4][2] = {};

    const short* gA0 = A  + (size_t)(m0 +      wave * 8 + lrow) * K + swz;
    const short* gA1 = A  + (size_t)(m0 + 32 + wave * 8 + lrow) * K + swz;
    const short* gB[4];
#pragma unroll
    for (int h = 0; h < 4; h++)
        gB[h] = Bw + (size_t)(n0 + h * 32 + wave * 8 + lrow) * K + swz;

    for (int k0 = 0; k0 < K; k0 += 64) {
        __builtin_amdgcn_global_load_lds(GCAST(gA0 + k0), LCAST(&As[(wave * 8) * 64]),        16, 0, 0);
        __builtin_amdgcn_global_load_lds(GCAST(gA1 + k0), LCAST(&As[(32 + wave * 8) * 64]),   16, 0, 0);
#pragma unroll
        for (int h = 0; h < 4; h++)
            __builtin_amdgcn_global_load_lds(GCAST(gB[h] + k0), LCAST(&Bs[(h * 32 + wave * 8) * 64]), 16, 0, 0);
        __syncthreads();
        shortx8 af[2][4], bw[2][2];
#pragma unroll
        for (int ks = 0; ks < 2; ks++) {
#pragma unroll
            for (int i = 0; i < 4; i++) af[ks][i] = read8(As, i * 16 + lm, ks * 32 + q * 8);
#pragma unroll
            for (int j = 0; j < 2; j++) bw[ks][j] = read8(Bs, wc + j * 16 + lm, ks * 32 + q * 8);
        }
#pragma unroll
        for (int ks = 0; ks < 2; ks++)
#pragma unroll
            for (int i = 0; i < 4; i++)
#pragma unroll
                for (int j = 0; j < 2; j++)
                    acc[i][j] = __builtin_amdgcn_mfma_f32_16x16x32_bf16(af[ks][i], bw[ks][j], acc[i][j], 0, 0, 0);
        __syncthreads();
    }
#pragma unroll
    for (int i = 0; i < 4; i++) {
        int rb = m0 + i * 16 + q * 4;
#pragma unroll
        for (int j = 0; j < 2; j++) {
            int col = n0 + wc + j * 16 + lm;
            float bv = bias[col];
#pragma unroll
            for (int r = 0; r < 4; r++)
                C[(size_t)(rb + r) * N + col] = acc[i][j][r] + bv;
        }
    }
}

__global__ __launch_bounds__(256) void gemm1_fused(const short* __restrict__ A,
                                                   const short* __restrict__ Bw,
                                                   const float* __restrict__ bias,
                                                   short* __restrict__ qb,
                                                   short* __restrict__ kb,
                                                   short* __restrict__ kTb,
                                                   short* __restrict__ vTb,
                                                   float* __restrict__ gateb) {
    __shared__ __align__(16) short As[128 * 64];
    __shared__ __align__(16) short Bs[128 * 64];
    const int K = DM;
    const int tid  = threadIdx.x;
    const int wave = tid >> 6, lane = tid & 63;
    const int m0 = blockIdx.y * 128;
    const int n0 = blockIdx.x * 128;
    const int lrow = lane >> 3;
    const int swz  = ((lane & 7) ^ lrow) << 3;
    const int lm = lane & 15, q = lane >> 4;
    const int wr = (wave >> 1) * 64;
    const int wc = (wave & 1) * 64;
    floatx4 acc[4][4] = {};

    const short* gA[4];
    const short* gB[4];
#pragma unroll
    for (int g = 0; g < 4; g++)
        gA[g] = A  + (size_t)(m0 + g * 32 + wave * 8 + lrow) * K + swz;
#pragma unroll
    for (int h = 0; h < 4; h++)
        gB[h] = Bw + (size_t)(n0 + h * 32 + wave * 8 + lrow) * K + swz;

    for (int k0 = 0; k0 < K; k0 += 64) {
#pragma unroll
        for (int g = 0; g < 4; g++)
            __builtin_amdgcn_global_load_lds(GCAST(gA[g] + k0), LCAST(&As[(g * 32 + wave * 8) * 64]), 16, 0, 0);
#pragma unroll
        for (int h = 0; h < 4; h++)
            __builtin_amdgcn_global_load_lds(GCAST(gB[h] + k0), LCAST(&Bs[(h * 32 + wave * 8) * 64]), 16, 0, 0);
        __syncthreads();
        shortx8 af[2][4], bw[2][4];
#pragma unroll
        for (int ks = 0; ks < 2; ks++) {
#pragma unroll
            for (int i = 0; i < 4; i++) af[ks][i] = read8(As, wr + i * 16 + lm, ks * 32 + q * 8);
#pragma unroll
            for (int j = 0; j < 4; j++) bw[ks][j] = read8(Bs, wc + j * 16 + lm, ks * 32 + q * 8);
        }
#pragma unroll
        for (int ks = 0; ks < 2; ks++)
#pragma unroll
            for (int i = 0; i < 4; i++)
#pragma unroll
                for (int j = 0; j < 4; j++)
                    acc[i][j] = __builtin_amdgcn_mfma_f32_16x16x32_bf16(af[ks][i], bw[ks][j], acc[i][j], 0, 0, 0);
        __syncthreads();
    }

    const int bIdx = m0 >> 11;
    const int bh0  = bIdx * H_;
#pragma unroll
    for (int i = 0; i < 4; i++) {
        int s0 = (m0 & (S_ - 1)) + wr + i * 16 + q * 4;
#pragma unroll
        for (int j = 0; j < 4; j++) {
            int col = n0 + wc + j * 16 + lm;
            float bv = (col < PROJ) ? bias[col] : 0.f;
            float vals[4];
#pragma unroll
            for (int r = 0; r < 4; r++) vals[r] = acc[i][j][r] + bv;
            if (col < 512) {
                int h = col >> 6, vd = col & 63;
                short tmp[4];
#pragma unroll
                for (int r = 0; r < 4; r++) tmp[r] = f2bf(vals[r]);
                *(shortx4*)&vTb[((size_t)(bh0 + h) * 64 + vd) * S_ + s0] = *(shortx4*)tmp;
            } else if (col < 1024) {
                int h = (col >> 6) - 8, d = col & 63;
                size_t rb = ((size_t)(bh0 + h) * S_ + s0) * 64 + d;
#pragma unroll
                for (int r = 0; r < 4; r++) qb[rb + (size_t)r * 64] = f2bf(vals[r]);
            } else if (col < 1536) {
                int h = (col >> 6) - 16, d = col & 63;
                size_t rb = ((size_t)(bh0 + h) * S_ + s0) * 64 + d;
                short tmp[4];
#pragma unroll
                for (int r = 0; r < 4; r++) { tmp[r] = f2bf(vals[r]); kb[rb + (size_t)r * 64] = tmp[r]; }
                *(shortx4*)&kTb[((size_t)(bh0 + h) * 64 + d) * S_ + s0] = *(shortx4*)tmp;
            } else if (col < PROJ) {
                int h = col - 1536;
                float g[4];
#pragma unroll
                for (int r = 0; r < 4; r++) g[r] = __expf(-__expf(vals[r]));
                *(float4*)&gateb[(size_t)(bh0 + h) * S_ + s0] = make_float4(g[0], g[1], g[2], g[3]);
            }
        }
    }
}

__global__ __launch_bounds__(256) void chunk_kv_mfma(const short* __restrict__ vTb,
                                                     const short* __restrict__ kTb,
                                                     float* __restrict__ kvbuf) {
    __shared__ __align__(16) short VT[64 * 64];
    __shared__ __align__(16) short KT[64 * 64];
    const int blk = blockIdx.x;
    const int c = blk & (NC - 1), bh = blk >> 5;
    const int base = c * CHK;
    const int tid = threadIdx.x, wave = tid >> 6, lane = tid & 63;
    const int lrow = lane >> 3, lgrp = lane & 7;

#pragma unroll
    for (int half = 0; half < 2; half++) {
        int v0 = wave * 8 + half * 32;
        int row = v0 + lrow;
        int gcol = ((lgrp ^ (row & 7)) << 3);
        __builtin_amdgcn_global_load_lds(GCAST(vTb + ((size_t)(bh * 64 + row)) * S_ + base + gcol),
                                         LCAST(&VT[v0 * 64]), 16, 0, 0);
        __builtin_amdgcn_global_load_lds(GCAST(kTb + ((size_t)(bh * 64 + row)) * S_ + base + gcol),
                                         LCAST(&KT[v0 * 64]), 16, 0, 0);
    }
    __syncthreads();

    const int lm = lane & 15, q = lane >> 4;
    const int wr = (wave >> 1) * 32, wc = (wave & 1) * 32;
    floatx4 acc[2][2] = {};
#pragma unroll
    for (int ks = 0; ks < 2; ks++) {
        shortx8 a[2], b2[2];
#pragma unroll
        for (int i = 0; i < 2; i++) a[i]  = read8(VT, wr + i * 16 + lm, ks * 32 + q * 8);
#pragma unroll
        for (int j = 0; j < 2; j++) b2[j] = read8(KT, wc + j * 16 + lm, ks * 32 + q * 8);
#pragma unroll
        for (int i = 0; i < 2; i++)
#pragma unroll
            for (int j = 0; j < 2; j++)
                acc[i][j] = __builtin_amdgcn_mfma_f32_16x16x32_bf16(a[i], b2[j], acc[i][j], 0, 0, 0);
    }
    float* outp = kvbuf + ((size_t)blk << 12);
#pragma unroll
    for (int i = 0; i < 2; i++)
#pragma unroll
        for (int j = 0; j < 2; j++)
#pragma unroll
            for (int r = 0; r < 4; r++)
                outp[(wr + i * 16 + q * 4 + r) * 64 + wc + j * 16 + lm] = acc[i][j][r];
}

__global__ __launch_bounds__(256) void scan_groups(const float* __restrict__ kvbuf,
                                                   float* __restrict__ kvg) {
    const int blk = blockIdx.x;
    const int bh = blk >> 4, seg = blk & 15;
    const int e = seg * 256 + threadIdx.x;
    const float* src = kvbuf + (((size_t)bh * NC) << 12) + e;
    float* dst = kvg + (((size_t)bh * 8) << 12) + e;
    float run = 0.f;
#pragma unroll
    for (int g = 0; g < 8; g++) {
        dst[(size_t)g << 12] = run;
#pragma unroll
        for (int cc = 0; cc < 4; cc++)
            run += src[(size_t)(g * 4 + cc) << 12];
    }
}

__global__ __launch_bounds__(256) void attn_mfma(const short* __restrict__ qb,
                                                 const short* __restrict__ kb,
                                                 const short* __restrict__ vTb,
                                                 const float* __restrict__ gateb,
                                                 const float* __restrict__ kvbuf,
                                                 const float* __restrict__ kvg,
                                                 short* __restrict__ ctxb) {
    __shared__ __align__(16) short Qs[64 * 64];
    __shared__ __align__(16) short Ks[64 * 64];
    __shared__ __align__(16) short VTs[64 * 64];
    __shared__ __align__(16) short Phi[64 * 64];
    __shared__ __align__(16) short Plo[64 * 64];
    __shared__ __align__(16) short Sb[64 * 72];
    __shared__ float gs[64];
    const int blk = blockIdx.x;
    const int bh = blk & (BH - 1);
    const int c  = (NC - 1) - (blk >> 4);
    const int base = c * CHK;
    const int tid = threadIdx.x, wave = tid >> 6, lane = tid & 63;
    const int lrow = lane >> 3, lgrp = lane & 7;

#pragma unroll
    for (int half = 0; half < 2; half++) {
        int v0 = wave * 8 + half * 32;
        int row = v0 + lrow;
        int gcol = ((lgrp ^ (row & 7)) << 3);
        __builtin_amdgcn_global_load_lds(GCAST(qb + ((size_t)bh * S_ + base + row) * 64 + gcol),
                                         LCAST(&Qs[v0 * 64]), 16, 0, 0);
        __builtin_amdgcn_global_load_lds(GCAST(kb + ((size_t)bh * S_ + base + row) * 64 + gcol),
                                         LCAST(&Ks[v0 * 64]), 16, 0, 0);
        __builtin_amdgcn_global_load_lds(GCAST(vTb + ((size_t)(bh * 64 + row)) * S_ + base + gcol),
                                         LCAST(&VTs[v0 * 64]), 16, 0, 0);
    }

    float pacc[16];
    {
        const float* gp = kvg + (((size_t)bh * 8 + (c >> 2)) << 12) + tid;
#pragma unroll
        for (int it = 0; it < 16; it++) pacc[it] = gp[it * 256];
        const float* kvb = kvbuf + (((size_t)bh * NC) << 12) + tid;
        for (int cp = c & ~3; cp < c; cp++) {
            const float* p = kvb + ((size_t)cp << 12);
#pragma unroll
            for (int it = 0; it < 16; it++) pacc[it] += p[it * 256];
        }
    }
#pragma unroll
    for (int it = 0; it < 16; it++) {
        int idx = it * 256 + tid;
        int v = idx >> 6, d = idx & 63;
        float f = pacc[it];
        short hi = f2bf(f);
        short lo = f2bf(f - bf2f(hi));
        int sw = v * 64 + (((d >> 3) ^ (v & 7)) << 3) + (d & 7);
        Phi[sw] = hi; Plo[sw] = lo;
    }
    if (tid < 64) gs[tid] = gateb[(size_t)bh * S_ + base + tid];
    __syncthreads();

    const int lm = lane & 15, q = lane >> 4;
    const int wr = (wave >> 1) * 32, wc = (wave & 1) * 32;

    floatx4 sacc[2][2] = {};
#pragma unroll
    for (int ks = 0; ks < 2; ks++) {
        shortx8 qa[2], kf[2];
#pragma unroll
        for (int i = 0; i < 2; i++) qa[i] = read8(Qs, wr + i * 16 + lm, ks * 32 + q * 8);
#pragma unroll
        for (int j = 0; j < 2; j++) kf[j] = read8(Ks, wc + j * 16 + lm, ks * 32 + q * 8);
#pragma unroll
        for (int i = 0; i < 2; i++)
#pragma unroll
            for (int j = 0; j < 2; j++)
                sacc[i][j] = __builtin_amdgcn_mfma_f32_16x16x32_bf16(qa[i], kf[j], sacc[i][j], 0, 0, 0);
    }
#pragma unroll
    for (int i = 0; i < 2; i++)
#pragma unroll
        for (int j = 0; j < 2; j++)
#pragma unroll
            for (int r = 0; r < 4; r++) {
                int s = wr + i * 16 + q * 4 + r;
                int t = wc + j * 16 + lm;
                Sb[s * 72 + t] = f2bf(t <= s ? sacc[i][j][r] : 0.f);
            }
    __syncthreads();

    floatx4 oacc[2][2] = {};
#pragma unroll
    for (int ks = 0; ks < 2; ks++) {
        shortx8 sa[2], vb[2];
#pragma unroll
        for (int i = 0; i < 2; i++)
            sa[i] = *(const shortx8*)&Sb[(wr + i * 16 + lm) * 72 + ks * 32 + q * 8];
#pragma unroll
        for (int j = 0; j < 2; j++) vb[j] = read8(VTs, wc + j * 16 + lm, ks * 32 + q * 8);
#pragma unroll
        for (int i = 0; i < 2; i++)
#pragma unroll
            for (int j = 0; j < 2; j++)
                oacc[i][j] = __builtin_amdgcn_mfma_f32_16x16x32_bf16(sa[i], vb[j], oacc[i][j], 0, 0, 0);
    }
#pragma unroll
    for (int ks = 0; ks < 2; ks++) {
        shortx8 qa[2], ph[2], pl[2];
#pragma unroll
        for (int i = 0; i < 2; i++) qa[i] = read8(Qs, wr + i * 16 + lm, ks * 32 + q * 8);
#pragma unroll
        for (int j = 0; j < 2; j++) {
            ph[j] = read8(Phi, wc + j * 16 + lm, ks * 32 + q * 8);
            pl[j] = read8(Plo, wc + j * 16 + lm, ks * 32 + q * 8);
        }
#pragma unroll
        for (int i = 0; i < 2; i++)
#pragma unroll
            for (int j = 0; j < 2; j++) {
                oacc[i][j] = __builtin_amdgcn_mfma_f32_16x16x32_bf16(qa[i], ph[j], oacc[i][j], 0, 0, 0);
                oacc[i][j] = __builtin_amdgcn_mfma_f32_16x16x32_bf16(qa[i], pl[j], oacc[i][j], 0, 0, 0);
            }
    }
    const size_t tok0 = (size_t)(bh >> 3) * S_ + base;
    const int h = bh & 7;
#pragma unroll
    for (int i = 0; i < 2; i++)
#pragma unroll
        for (int j = 0; j < 2; j++)
#pragma unroll
            for (int r = 0; r < 4; r++) {
                int s = wr + i * 16 + q * 4 + r;
                int v = wc + j * 16 + lm;
                ctxb[(tok0 + s) * DM + h * 64 + v] = f2bf(gs[s] * oacc[i][j][r]);
            }
}

// ---------------------------------------------------------------------------
extern "C" void kernel_launch(void* const* d_in, const int* in_sizes, int n_in,
                              void* d_out, int out_size, void* d_ws, size_t ws_size,
                              hipStream_t stream) {
    const float* x       = (const float*)d_in[0];
    const float* Wvqkn_w = (const float*)d_in[1];
    const float* Wvqkn_b = (const float*)d_in[2];
    const float* out_w   = (const float*)d_in[3];
    const float* out_b   = (const float*)d_in[4];
    float* out = (float*)d_out;

    unsigned* barcnt = (unsigned*)d_ws;                   // 1024 B (8 slots x 128B)
    float* kvbuf = (float*)((char*)d_ws + 1024);          // 16*32*4096 f32
    float* kvg   = kvbuf + (size_t)BH * NC * 4096;        // 16*8*4096 f32 (fallback only)
    short* xb    = (short*)(kvg + (size_t)BH * 8 * 4096);
    short* w1b   = xb   + (size_t)BS_ * DM;
    short* w2b   = w1b  + (size_t)NPAD1 * DM;
    short* ctxb  = w2b  + (size_t)DM * DM;
    short* qb    = ctxb + (size_t)BS_ * DM;
    short* kb    = qb   + (size_t)BH * S_ * 64;
    short* kTb   = kb   + (size_t)BH * S_ * 64;
    short* vTb   = kTb  + (size_t)BH * S_ * 64;
    float* gateb = (float*)(vTb + (size_t)BH * S_ * 64);

    hipMemsetAsync(barcnt, 0, 1024, stream);

    void* args[] = {
        (void*)&x, (void*)&Wvqkn_w, (void*)&out_w, (void*)&Wvqkn_b, (void*)&out_b,
        (void*)&xb, (void*)&w1b, (void*)&w2b,
        (void*)&qb, (void*)&kb, (void*)&kTb, (void*)&vTb, (void*)&gateb,
        (void*)&kvbuf, (void*)&ctxb, (void*)&out, (void*)&barcnt
    };
    hipError_t err = hipLaunchCooperativeKernel((const void*)mega, dim3(NBLK), dim3(256),
                                                args, 0, stream);
    if (err != hipSuccess) {
        // Fallback: verified 6-kernel pipeline.
        convert_all<<<(int)((E1 + E2 + E3) / 8 / 256), 256, 0, stream>>>(
            x, Wvqkn_w, out_w, xb, w1b, w2b);
        gemm1_fused<<<dim3(NPAD1 / 128, BS_ / 128), 256, 0, stream>>>(
            xb, w1b, Wvqkn_b, qb, kb, kTb, vTb, gateb);
        chunk_kv_mfma<<<BH * NC, 256, 0, stream>>>(vTb, kTb, kvbuf);
        scan_groups<<<BH * 16, 256, 0, stream>>>(kvbuf, kvg);
        attn_mfma<<<BH * NC, 256, 0, stream>>>(qb, kb, vTb, gateb, kvbuf, kvg, ctxb);
        gemm_mfma64<<<dim3(DM / 128, BS_ / 64), 256, 0, stream>>>(ctxb, w2b, out_b, out, DM, DM);
    }
}

// Round 4
// 118.683 us; speedup vs baseline: 4.7050x; 4.7050x over previous
//
#include <hip/hip_runtime.h>
#include <hip/hip_bf16.h>
#include <math.h>

#define B_    2
#define S_    2048
#define DM    512
#define H_    8
#define PROJ  1544
#define NPAD1 1664        // 13*128
#define CHK   64
#define NC    32
#define BS_   4096
#define BH    16

typedef __attribute__((ext_vector_type(8))) short shortx8;
typedef __attribute__((ext_vector_type(4))) short shortx4;
typedef __attribute__((ext_vector_type(4))) float floatx4;

#define GCAST(p) ((const __attribute__((address_space(1))) void*)(p))
#define LCAST(p) ((__attribute__((address_space(3))) void*)(p))

__device__ inline short f2bf(float f) {
    __hip_bfloat16 h = __float2bfloat16(f);
    return *(short*)&h;
}
__device__ inline float bf2f(short s) {
    __hip_bfloat16 h = *(__hip_bfloat16*)&s;
    return __bfloat162float(h);
}
// Read 8 contiguous bf16 (k mult of 8) from a 64-k-wide tile whose 16B groups
// are XOR-swizzled by row: element (row,k) lives at group (k>>3)^(row&7).
__device__ inline shortx8 read8(const short* buf, int row, int k) {
    return *(const shortx8*)&buf[row * 64 + ((((k >> 3) ^ (row & 7))) << 3)];
}

// ---------------------------------------------------------------------------
// One fused fp32->bf16 convert for x, W1 (zero row-pad to NPAD1), W2.
// ---------------------------------------------------------------------------
#define E1 ((size_t)BS_ * DM)
#define E2 ((size_t)NPAD1 * DM)
#define E3 ((size_t)DM * DM)
__global__ __launch_bounds__(256) void convert_all(const float* __restrict__ x,
                                                   const float* __restrict__ w1,
                                                   const float* __restrict__ w2,
                                                   short* __restrict__ xb,
                                                   short* __restrict__ w1b,
                                                   short* __restrict__ w2b) {
    size_t e = ((size_t)blockIdx.x * 256 + threadIdx.x) * 8;
    const float* src;
    short* dst;
    bool zero = false;
    if (e < E1) { src = x + e; dst = xb + e; }
    else if (e < E1 + E2) {
        size_t o = e - E1;
        dst = w1b + o;
        size_t row = o >> 9;
        if (row < PROJ) src = w1 + o; else { src = w1; zero = true; }
    } else if (e < E1 + E2 + E3) {
        size_t o = e - E1 - E2;
        src = w2 + o; dst = w2b + o;
    } else return;
    short out[8];
    if (zero) {
#pragma unroll
        for (int i = 0; i < 8; i++) out[i] = 0;
    } else {
        float4 f0 = *(const float4*)src;
        float4 f1 = *(const float4*)(src + 4);
        out[0] = f2bf(f0.x); out[1] = f2bf(f0.y); out[2] = f2bf(f0.z); out[3] = f2bf(f0.w);
        out[4] = f2bf(f1.x); out[5] = f2bf(f1.y); out[6] = f2bf(f1.z); out[7] = f2bf(f1.w);
    }
    *(shortx8*)dst = *(shortx8*)out;
}

// ---------------------------------------------------------------------------
// 64x128-tile, BK=64, XOR-swizzled bf16 MFMA GEMM (final out-proj, N=512).
// ---------------------------------------------------------------------------
__global__ __launch_bounds__(256) void gemm_mfma64(const short* __restrict__ A,
                                                   const short* __restrict__ Bw,
                                                   const float* __restrict__ bias,
                                                   float* __restrict__ C,
                                                   int N, int K) {
    __shared__ __align__(16) short As[64 * 64];
    __shared__ __align__(16) short Bs[128 * 64];
    const int tid  = threadIdx.x;
    const int wave = tid >> 6, lane = tid & 63;
    const int m0 = blockIdx.y * 64;
    const int n0 = blockIdx.x * 128;
    const int lrow = lane >> 3;                   // 0..7
    const int swz  = ((lane & 7) ^ lrow) << 3;    // global k-offset (elems)
    const int lm = lane & 15, q = lane >> 4;
    const int wc = wave * 32;
    floatx4 acc[4][2] = {};

    const short* gA0 = A  + (size_t)(m0 +      wave * 8 + lrow) * K + swz;
    const short* gA1 = A  + (size_t)(m0 + 32 + wave * 8 + lrow) * K + swz;
    const short* gB[4];
#pragma unroll
    for (int h = 0; h < 4; h++)
        gB[h] = Bw + (size_t)(n0 + h * 32 + wave * 8 + lrow) * K + swz;

    for (int k0 = 0; k0 < K; k0 += 64) {
        __builtin_amdgcn_global_load_lds(GCAST(gA0 + k0), LCAST(&As[(wave * 8) * 64]),        16, 0, 0);
        __builtin_amdgcn_global_load_lds(GCAST(gA1 + k0), LCAST(&As[(32 + wave * 8) * 64]),   16, 0, 0);
#pragma unroll
        for (int h = 0; h < 4; h++)
            __builtin_amdgcn_global_load_lds(GCAST(gB[h] + k0), LCAST(&Bs[(h * 32 + wave * 8) * 64]), 16, 0, 0);
        __syncthreads();
        shortx8 af[2][4], bw[2][2];
#pragma unroll
        for (int ks = 0; ks < 2; ks++) {
#pragma unroll
            for (int i = 0; i < 4; i++) af[ks][i] = read8(As, i * 16 + lm, ks * 32 + q * 8);
#pragma unroll
            for (int j = 0; j < 2; j++) bw[ks][j] = read8(Bs, wc + j * 16 + lm, ks * 32 + q * 8);
        }
#pragma unroll
        for (int ks = 0; ks < 2; ks++)
#pragma unroll
            for (int i = 0; i < 4; i++)
#pragma unroll
                for (int j = 0; j < 2; j++)
                    acc[i][j] = __builtin_amdgcn_mfma_f32_16x16x32_bf16(af[ks][i], bw[ks][j], acc[i][j], 0, 0, 0);
        __syncthreads();
    }
#pragma unroll
    for (int i = 0; i < 4; i++) {
        int rb = m0 + i * 16 + q * 4;
#pragma unroll
        for (int j = 0; j < 2; j++) {
            int col = n0 + wc + j * 16 + lm;
            float bv = bias[col];
#pragma unroll
            for (int r = 0; r < 4; r++)
                C[(size_t)(rb + r) * N + col] = acc[i][j][r] + bv;
        }
    }
}

// ---------------------------------------------------------------------------
// gemm1: 128x128 tile, BK=64, m97 structure (wave grid 2x2, acc[4][4]),
// XOR-swizzled LDS, global_load_lds width=16, with fused epilogue producing
// q[bh][s][d], k[bh][t][d], kT[bh][d][s], vT[bh][v][s] (bf16), gate[bh][s] f32.
// ---------------------------------------------------------------------------
__global__ __launch_bounds__(256) void gemm1_fused(const short* __restrict__ A,
                                                   const short* __restrict__ Bw,
                                                   const float* __restrict__ bias,
                                                   short* __restrict__ qb,
                                                   short* __restrict__ kb,
                                                   short* __restrict__ kTb,
                                                   short* __restrict__ vTb,
                                                   float* __restrict__ gateb) {
    __shared__ __align__(16) short As[128 * 64];
    __shared__ __align__(16) short Bs[128 * 64];
    const int K = DM;
    const int tid  = threadIdx.x;
    const int wave = tid >> 6, lane = tid & 63;
    const int m0 = blockIdx.y * 128;
    const int n0 = blockIdx.x * 128;
    const int lrow = lane >> 3;                   // 0..7
    const int swz  = ((lane & 7) ^ lrow) << 3;    // global k-offset (elems)
    const int lm = lane & 15, q = lane >> 4;
    const int wr = (wave >> 1) * 64;              // wave's A-row half
    const int wc = (wave & 1) * 64;               // wave's B-col half
    floatx4 acc[4][4] = {};

    const short* gA[4];
    const short* gB[4];
#pragma unroll
    for (int g = 0; g < 4; g++)
        gA[g] = A  + (size_t)(m0 + g * 32 + wave * 8 + lrow) * K + swz;
#pragma unroll
    for (int h = 0; h < 4; h++)
        gB[h] = Bw + (size_t)(n0 + h * 32 + wave * 8 + lrow) * K + swz;

    for (int k0 = 0; k0 < K; k0 += 64) {
#pragma unroll
        for (int g = 0; g < 4; g++)
            __builtin_amdgcn_global_load_lds(GCAST(gA[g] + k0), LCAST(&As[(g * 32 + wave * 8) * 64]), 16, 0, 0);
#pragma unroll
        for (int h = 0; h < 4; h++)
            __builtin_amdgcn_global_load_lds(GCAST(gB[h] + k0), LCAST(&Bs[(h * 32 + wave * 8) * 64]), 16, 0, 0);
        __syncthreads();
        shortx8 af[2][4], bw[2][4];
#pragma unroll
        for (int ks = 0; ks < 2; ks++) {
#pragma unroll
            for (int i = 0; i < 4; i++) af[ks][i] = read8(As, wr + i * 16 + lm, ks * 32 + q * 8);
#pragma unroll
            for (int j = 0; j < 4; j++) bw[ks][j] = read8(Bs, wc + j * 16 + lm, ks * 32 + q * 8);
        }
#pragma unroll
        for (int ks = 0; ks < 2; ks++)
#pragma unroll
            for (int i = 0; i < 4; i++)
#pragma unroll
                for (int j = 0; j < 4; j++)
                    acc[i][j] = __builtin_amdgcn_mfma_f32_16x16x32_bf16(af[ks][i], bw[ks][j], acc[i][j], 0, 0, 0);
        __syncthreads();
    }

    const int bIdx = m0 >> 11;                    // batch (tile never straddles 2048)
    const int bh0  = bIdx * H_;
#pragma unroll
    for (int i = 0; i < 4; i++) {
        int s0 = (m0 & (S_ - 1)) + wr + i * 16 + q * 4;
#pragma unroll
        for (int j = 0; j < 4; j++) {
            int col = n0 + wc + j * 16 + lm;
            float bv = (col < PROJ) ? bias[col] : 0.f;
            float vals[4];
#pragma unroll
            for (int r = 0; r < 4; r++) vals[r] = acc[i][j][r] + bv;
            if (col < 512) {                       // v -> vT[bh][v][s]
                int h = col >> 6, vd = col & 63;
                short tmp[4];
#pragma unroll
                for (int r = 0; r < 4; r++) tmp[r] = f2bf(vals[r]);
                *(shortx4*)&vTb[((size_t)(bh0 + h) * 64 + vd) * S_ + s0] = *(shortx4*)tmp;
            } else if (col < 1024) {               // q -> q[bh][s][d]
                int h = (col >> 6) - 8, d = col & 63;
                size_t rb = ((size_t)(bh0 + h) * S_ + s0) * 64 + d;
#pragma unroll
                for (int r = 0; r < 4; r++) qb[rb + (size_t)r * 64] = f2bf(vals[r]);
            } else if (col < 1536) {               // k -> k[bh][t][d] and kT[bh][d][t]
                int h = (col >> 6) - 16, d = col & 63;
                size_t rb = ((size_t)(bh0 + h) * S_ + s0) * 64 + d;
                short tmp[4];
#pragma unroll
                for (int r = 0; r < 4; r++) { tmp[r] = f2bf(vals[r]); kb[rb + (size_t)r * 64] = tmp[r]; }
                *(shortx4*)&kTb[((size_t)(bh0 + h) * 64 + d) * S_ + s0] = *(shortx4*)tmp;
            } else if (col < PROJ) {               // n -> gate[bh][s]
                int h = col - 1536;
                float g[4];
#pragma unroll
                for (int r = 0; r < 4; r++) g[r] = __expf(-__expf(vals[r]));
                *(float4*)&gateb[(size_t)(bh0 + h) * S_ + s0] = make_float4(g[0], g[1], g[2], g[3]);
            }
        }
    }
}

// ---------------------------------------------------------------------------
// Per-chunk state via MFMA: U[v][d] = sum_{s in chunk} V[s][v] * K[s][d]
// ---------------------------------------------------------------------------
__global__ __launch_bounds__(256) void chunk_kv_mfma(const short* __restrict__ vTb,
                                                     const short* __restrict__ kTb,
                                                     float* __restrict__ kvbuf) {
    __shared__ __align__(16) short VT[64 * 64];
    __shared__ __align__(16) short KT[64 * 64];
    const int blk = blockIdx.x;
    const int c = blk & (NC - 1), bh = blk >> 5;
    const int base = c * CHK;
    const int tid = threadIdx.x, wave = tid >> 6, lane = tid & 63;
    const int lrow = lane >> 3, lgrp = lane & 7;

#pragma unroll
    for (int half = 0; half < 2; half++) {
        int v0 = wave * 8 + half * 32;
        int row = v0 + lrow;
        int gcol = ((lgrp ^ (row & 7)) << 3);
        __builtin_amdgcn_global_load_lds(GCAST(vTb + ((size_t)(bh * 64 + row)) * S_ + base + gcol),
                                         LCAST(&VT[v0 * 64]), 16, 0, 0);
        __builtin_amdgcn_global_load_lds(GCAST(kTb + ((size_t)(bh * 64 + row)) * S_ + base + gcol),
                                         LCAST(&KT[v0 * 64]), 16, 0, 0);
    }
    __syncthreads();

    const int lm = lane & 15, q = lane >> 4;
    const int wr = (wave >> 1) * 32, wc = (wave & 1) * 32;
    floatx4 acc[2][2] = {};
#pragma unroll
    for (int ks = 0; ks < 2; ks++) {
        shortx8 a[2], b2[2];
#pragma unroll
        for (int i = 0; i < 2; i++) a[i]  = read8(VT, wr + i * 16 + lm, ks * 32 + q * 8);
#pragma unroll
        for (int j = 0; j < 2; j++) b2[j] = read8(KT, wc + j * 16 + lm, ks * 32 + q * 8);
#pragma unroll
        for (int i = 0; i < 2; i++)
#pragma unroll
            for (int j = 0; j < 2; j++)
                acc[i][j] = __builtin_amdgcn_mfma_f32_16x16x32_bf16(a[i], b2[j], acc[i][j], 0, 0, 0);
    }
    float* outp = kvbuf + ((size_t)blk << 12);
#pragma unroll
    for (int i = 0; i < 2; i++)
#pragma unroll
        for (int j = 0; j < 2; j++)
#pragma unroll
            for (int r = 0; r < 4; r++)
                outp[(wr + i * 16 + q * 4 + r) * 64 + wc + j * 16 + lm] = acc[i][j][r];
}

// ---------------------------------------------------------------------------
// MFMA attention chunk. Prefix = direct fp32 sum of the <=31 preceding chunk
// states straight from kvbuf (L2-resident) — scan kernel eliminated.
// Verified inside R3's mega (passed, absmax 1.0).
// ---------------------------------------------------------------------------
__global__ __launch_bounds__(256) void attn_mfma(const short* __restrict__ qb,
                                                 const short* __restrict__ kb,
                                                 const short* __restrict__ vTb,
                                                 const float* __restrict__ gateb,
                                                 const float* __restrict__ kvbuf,
                                                 short* __restrict__ ctxb) {
    __shared__ __align__(16) short Qs[64 * 64];
    __shared__ __align__(16) short Ks[64 * 64];
    __shared__ __align__(16) short VTs[64 * 64];
    __shared__ __align__(16) short Phi[64 * 64];
    __shared__ __align__(16) short Plo[64 * 64];
    __shared__ __align__(16) short Sb[64 * 72];
    __shared__ float gs[64];
    const int blk = blockIdx.x;
    const int bh = blk & (BH - 1);
    const int c  = (NC - 1) - (blk >> 4);   // heavy-prefix chunks start first
    const int base = c * CHK;
    const int tid = threadIdx.x, wave = tid >> 6, lane = tid & 63;
    const int lrow = lane >> 3, lgrp = lane & 7;

#pragma unroll
    for (int half = 0; half < 2; half++) {
        int v0 = wave * 8 + half * 32;
        int row = v0 + lrow;
        int gcol = ((lgrp ^ (row & 7)) << 3);
        __builtin_amdgcn_global_load_lds(GCAST(qb + ((size_t)bh * S_ + base + row) * 64 + gcol),
                                         LCAST(&Qs[v0 * 64]), 16, 0, 0);
        __builtin_amdgcn_global_load_lds(GCAST(kb + ((size_t)bh * S_ + base + row) * 64 + gcol),
                                         LCAST(&Ks[v0 * 64]), 16, 0, 0);
        __builtin_amdgcn_global_load_lds(GCAST(vTb + ((size_t)(bh * 64 + row)) * S_ + base + gcol),
                                         LCAST(&VTs[v0 * 64]), 16, 0, 0);
    }

    // Exclusive prefix over preceding chunk states, straight from kvbuf.
    float pacc[16];
#pragma unroll
    for (int it = 0; it < 16; it++) pacc[it] = 0.f;
    {
        const float* kvb = kvbuf + (((size_t)bh * NC) << 12) + tid;
        for (int cp = 0; cp < c; cp++) {
            const float* p = kvb + ((size_t)cp << 12);
#pragma unroll
            for (int it = 0; it < 16; it++) pacc[it] += p[it * 256];
        }
    }
#pragma unroll
    for (int it = 0; it < 16; it++) {
        int idx = it * 256 + tid;
        int v = idx >> 6, d = idx & 63;
        float f = pacc[it];
        short hi = f2bf(f);
        short lo = f2bf(f - bf2f(hi));
        int sw = v * 64 + (((d >> 3) ^ (v & 7)) << 3) + (d & 7);
        Phi[sw] = hi; Plo[sw] = lo;
    }
    if (tid < 64) gs[tid] = gateb[(size_t)bh * S_ + base + tid];
    __syncthreads();

    const int lm = lane & 15, q = lane >> 4;
    const int wr = (wave >> 1) * 32, wc = (wave & 1) * 32;

    // Phase 1: S quadrant = Q K^T, causal mask, -> Sb bf16
    floatx4 sacc[2][2] = {};
#pragma unroll
    for (int ks = 0; ks < 2; ks++) {
        shortx8 qa[2], kf[2];
#pragma unroll
        for (int i = 0; i < 2; i++) qa[i] = read8(Qs, wr + i * 16 + lm, ks * 32 + q * 8);
#pragma unroll
        for (int j = 0; j < 2; j++) kf[j] = read8(Ks, wc + j * 16 + lm, ks * 32 + q * 8);
#pragma unroll
        for (int i = 0; i < 2; i++)
#pragma unroll
            for (int j = 0; j < 2; j++)
                sacc[i][j] = __builtin_amdgcn_mfma_f32_16x16x32_bf16(qa[i], kf[j], sacc[i][j], 0, 0, 0);
    }
#pragma unroll
    for (int i = 0; i < 2; i++)
#pragma unroll
        for (int j = 0; j < 2; j++)
#pragma unroll
            for (int r = 0; r < 4; r++) {
                int s = wr + i * 16 + q * 4 + r;
                int t = wc + j * 16 + lm;
                Sb[s * 72 + t] = f2bf(t <= s ? sacc[i][j][r] : 0.f);
            }
    __syncthreads();

    // Phase 2: O = S.V + Q.(Phi+Plo)
    floatx4 oacc[2][2] = {};
#pragma unroll
    for (int ks = 0; ks < 2; ks++) {
        shortx8 sa[2], vb[2];
#pragma unroll
        for (int i = 0; i < 2; i++)
            sa[i] = *(const shortx8*)&Sb[(wr + i * 16 + lm) * 72 + ks * 32 + q * 8];
#pragma unroll
        for (int j = 0; j < 2; j++) vb[j] = read8(VTs, wc + j * 16 + lm, ks * 32 + q * 8);
#pragma unroll
        for (int i = 0; i < 2; i++)
#pragma unroll
            for (int j = 0; j < 2; j++)
                oacc[i][j] = __builtin_amdgcn_mfma_f32_16x16x32_bf16(sa[i], vb[j], oacc[i][j], 0, 0, 0);
    }
#pragma unroll
    for (int ks = 0; ks < 2; ks++) {
        shortx8 qa[2], ph[2], pl[2];
#pragma unroll
        for (int i = 0; i < 2; i++) qa[i] = read8(Qs, wr + i * 16 + lm, ks * 32 + q * 8);
#pragma unroll
        for (int j = 0; j < 2; j++) {
            ph[j] = read8(Phi, wc + j * 16 + lm, ks * 32 + q * 8);
            pl[j] = read8(Plo, wc + j * 16 + lm, ks * 32 + q * 8);
        }
#pragma unroll
        for (int i = 0; i < 2; i++)
#pragma unroll
            for (int j = 0; j < 2; j++) {
                oacc[i][j] = __builtin_amdgcn_mfma_f32_16x16x32_bf16(qa[i], ph[j], oacc[i][j], 0, 0, 0);
                oacc[i][j] = __builtin_amdgcn_mfma_f32_16x16x32_bf16(qa[i], pl[j], oacc[i][j], 0, 0, 0);
            }
    }
    const size_t tok0 = (size_t)(bh >> 3) * S_ + base;
    const int h = bh & 7;
#pragma unroll
    for (int i = 0; i < 2; i++)
#pragma unroll
        for (int j = 0; j < 2; j++)
#pragma unroll
            for (int r = 0; r < 4; r++) {
                int s = wr + i * 16 + q * 4 + r;
                int v = wc + j * 16 + lm;
                ctxb[(tok0 + s) * DM + h * 64 + v] = f2bf(gs[s] * oacc[i][j][r]);
            }
}

// ---------------------------------------------------------------------------
extern "C" void kernel_launch(void* const* d_in, const int* in_sizes, int n_in,
                              void* d_out, int out_size, void* d_ws, size_t ws_size,
                              hipStream_t stream) {
    const float* x       = (const float*)d_in[0];
    const float* Wvqkn_w = (const float*)d_in[1];
    const float* Wvqkn_b = (const float*)d_in[2];
    const float* out_w   = (const float*)d_in[3];
    const float* out_b   = (const float*)d_in[4];
    float* out = (float*)d_out;

    float* kvbuf = (float*)d_ws;                          // 16*32*4096 f32
    short* xb    = (short*)(kvbuf + (size_t)BH * NC * 4096);
    short* w1b   = xb   + (size_t)BS_ * DM;
    short* w2b   = w1b  + (size_t)NPAD1 * DM;
    short* ctxb  = w2b  + (size_t)DM * DM;
    short* qb    = ctxb + (size_t)BS_ * DM;
    short* kb    = qb   + (size_t)BH * S_ * 64;
    short* kTb   = kb   + (size_t)BH * S_ * 64;
    short* vTb   = kTb  + (size_t)BH * S_ * 64;
    float* gateb = (float*)(vTb + (size_t)BH * S_ * 64);

    convert_all<<<(int)((E1 + E2 + E3) / 8 / 256), 256, 0, stream>>>(
        x, Wvqkn_w, out_w, xb, w1b, w2b);

    gemm1_fused<<<dim3(NPAD1 / 128, BS_ / 128), 256, 0, stream>>>(
        xb, w1b, Wvqkn_b, qb, kb, kTb, vTb, gateb);

    chunk_kv_mfma<<<BH * NC, 256, 0, stream>>>(vTb, kTb, kvbuf);

    attn_mfma<<<BH * NC, 256, 0, stream>>>(qb, kb, vTb, gateb, kvbuf, ctxb);

    gemm_mfma64<<<dim3(DM / 128, BS_ / 64), 256, 0, stream>>>(ctxb, w2b, out_b, out, DM, DM);
}

// Round 5
// 112.384 us; speedup vs baseline: 4.9688x; 1.0561x over previous
//
#include <hip/hip_runtime.h>
#include <hip/hip_bf16.h>
#include <math.h>

#define B_    2
#define S_    2048
#define DM    512
#define H_    8
#define PROJ  1544
#define NPAD1 1664        // 13*128
#define CHK   64
#define NC    32
#define BS_   4096
#define BH    16

typedef __attribute__((ext_vector_type(8))) short shortx8;
typedef __attribute__((ext_vector_type(4))) short shortx4;
typedef __attribute__((ext_vector_type(4))) float floatx4;

#define GCAST(p) ((const __attribute__((address_space(1))) void*)(p))
#define LCAST(p) ((__attribute__((address_space(3))) void*)(p))

__device__ inline short f2bf(float f) {
    __hip_bfloat16 h = __float2bfloat16(f);
    return *(short*)&h;
}
__device__ inline float bf2f(short s) {
    __hip_bfloat16 h = *(__hip_bfloat16*)&s;
    return __bfloat162float(h);
}
// Read 8 contiguous bf16 (k mult of 8) from a 64-k-wide tile whose 16B groups
// are XOR-swizzled by row: element (row,k) lives at group (k>>3)^(row&7).
__device__ inline shortx8 read8(const short* buf, int row, int k) {
    return *(const shortx8*)&buf[row * 64 + ((((k >> 3) ^ (row & 7))) << 3)];
}

// ---------------------------------------------------------------------------
// One fused fp32->bf16 convert for x, W1 (zero row-pad to NPAD1), W2.
// ---------------------------------------------------------------------------
#define E1 ((size_t)BS_ * DM)
#define E2 ((size_t)NPAD1 * DM)
#define E3 ((size_t)DM * DM)
__global__ __launch_bounds__(256) void convert_all(const float* __restrict__ x,
                                                   const float* __restrict__ w1,
                                                   const float* __restrict__ w2,
                                                   short* __restrict__ xb,
                                                   short* __restrict__ w1b,
                                                   short* __restrict__ w2b) {
    size_t e = ((size_t)blockIdx.x * 256 + threadIdx.x) * 8;
    const float* src;
    short* dst;
    bool zero = false;
    if (e < E1) { src = x + e; dst = xb + e; }
    else if (e < E1 + E2) {
        size_t o = e - E1;
        dst = w1b + o;
        size_t row = o >> 9;
        if (row < PROJ) src = w1 + o; else { src = w1; zero = true; }
    } else if (e < E1 + E2 + E3) {
        size_t o = e - E1 - E2;
        src = w2 + o; dst = w2b + o;
    } else return;
    short out[8];
    if (zero) {
#pragma unroll
        for (int i = 0; i < 8; i++) out[i] = 0;
    } else {
        float4 f0 = *(const float4*)src;
        float4 f1 = *(const float4*)(src + 4);
        out[0] = f2bf(f0.x); out[1] = f2bf(f0.y); out[2] = f2bf(f0.z); out[3] = f2bf(f0.w);
        out[4] = f2bf(f1.x); out[5] = f2bf(f1.y); out[6] = f2bf(f1.z); out[7] = f2bf(f1.w);
    }
    *(shortx8*)dst = *(shortx8*)out;
}

// ---------------------------------------------------------------------------
// 64x128-tile, BK=64, XOR-swizzled bf16 MFMA GEMM (final out-proj, N=512).
// 2-phase double-buffered: stage next K-tile while computing current; ONE
// __syncthreads per K-step (its vmcnt(0) drains loads that had the whole
// read+MFMA phase to land). Buffer b^1 was last read before the previous
// barrier, so the overwrite is race-free.
// ---------------------------------------------------------------------------
__global__ __launch_bounds__(256) void gemm_mfma64(const short* __restrict__ A,
                                                   const short* __restrict__ Bw,
                                                   const float* __restrict__ bias,
                                                   float* __restrict__ C,
                                                   int N, int K) {
    __shared__ __align__(16) short As[2][64 * 64];
    __shared__ __align__(16) short Bs[2][128 * 64];
    const int tid  = threadIdx.x;
    const int wave = tid >> 6, lane = tid & 63;
    const int m0 = blockIdx.y * 64;
    const int n0 = blockIdx.x * 128;
    const int lrow = lane >> 3;                   // 0..7
    const int swz  = ((lane & 7) ^ lrow) << 3;    // global k-offset (elems)
    const int lm = lane & 15, q = lane >> 4;
    const int wc = wave * 32;
    floatx4 acc[4][2] = {};

    const short* gA0 = A  + (size_t)(m0 +      wave * 8 + lrow) * K + swz;
    const short* gA1 = A  + (size_t)(m0 + 32 + wave * 8 + lrow) * K + swz;
    const short* gB[4];
#pragma unroll
    for (int h = 0; h < 4; h++)
        gB[h] = Bw + (size_t)(n0 + h * 32 + wave * 8 + lrow) * K + swz;

    auto stage = [&](int b, int k0) {
        __builtin_amdgcn_global_load_lds(GCAST(gA0 + k0), LCAST(&As[b][(wave * 8) * 64]),      16, 0, 0);
        __builtin_amdgcn_global_load_lds(GCAST(gA1 + k0), LCAST(&As[b][(32 + wave * 8) * 64]), 16, 0, 0);
#pragma unroll
        for (int h = 0; h < 4; h++)
            __builtin_amdgcn_global_load_lds(GCAST(gB[h] + k0), LCAST(&Bs[b][(h * 32 + wave * 8) * 64]), 16, 0, 0);
    };

    const int nt = K >> 6;
    stage(0, 0);
    __syncthreads();
    for (int t = 0; t < nt; ++t) {
        const int cur = t & 1;
        if (t + 1 < nt) stage(cur ^ 1, (t + 1) << 6);
        shortx8 af[2][4], bw[2][2];
#pragma unroll
        for (int ks = 0; ks < 2; ks++) {
#pragma unroll
            for (int i = 0; i < 4; i++) af[ks][i] = read8(As[cur], i * 16 + lm, ks * 32 + q * 8);
#pragma unroll
            for (int j = 0; j < 2; j++) bw[ks][j] = read8(Bs[cur], wc + j * 16 + lm, ks * 32 + q * 8);
        }
#pragma unroll
        for (int ks = 0; ks < 2; ks++)
#pragma unroll
            for (int i = 0; i < 4; i++)
#pragma unroll
                for (int j = 0; j < 2; j++)
                    acc[i][j] = __builtin_amdgcn_mfma_f32_16x16x32_bf16(af[ks][i], bw[ks][j], acc[i][j], 0, 0, 0);
        __syncthreads();
    }
#pragma unroll
    for (int i = 0; i < 4; i++) {
        int rb = m0 + i * 16 + q * 4;
#pragma unroll
        for (int j = 0; j < 2; j++) {
            int col = n0 + wc + j * 16 + lm;
            float bv = bias[col];
#pragma unroll
            for (int r = 0; r < 4; r++)
                C[(size_t)(rb + r) * N + col] = acc[i][j][r] + bv;
        }
    }
}

// ---------------------------------------------------------------------------
// gemm1: 128x128 tile, BK=64, m97 structure (wave grid 2x2, acc[4][4]),
// XOR-swizzled LDS, global_load_lds width=16, 2-phase double-buffered
// (see gemm_mfma64 note), with fused epilogue producing q[bh][s][d],
// k[bh][t][d], kT[bh][d][s], vT[bh][v][s] (bf16), gate[bh][s] fp32.
// LDS 64KB -> 2 blocks/CU; grid is 416 blocks on 256 CUs so unaffected.
// ---------------------------------------------------------------------------
__global__ __launch_bounds__(256) void gemm1_fused(const short* __restrict__ A,
                                                   const short* __restrict__ Bw,
                                                   const float* __restrict__ bias,
                                                   short* __restrict__ qb,
                                                   short* __restrict__ kb,
                                                   short* __restrict__ kTb,
                                                   short* __restrict__ vTb,
                                                   float* __restrict__ gateb) {
    __shared__ __align__(16) short As[2][128 * 64];
    __shared__ __align__(16) short Bs[2][128 * 64];
    const int K = DM;
    const int tid  = threadIdx.x;
    const int wave = tid >> 6, lane = tid & 63;
    const int m0 = blockIdx.y * 128;
    const int n0 = blockIdx.x * 128;
    const int lrow = lane >> 3;                   // 0..7
    const int swz  = ((lane & 7) ^ lrow) << 3;    // global k-offset (elems)
    const int lm = lane & 15, q = lane >> 4;
    const int wr = (wave >> 1) * 64;              // wave's A-row half
    const int wc = (wave & 1) * 64;               // wave's B-col half
    floatx4 acc[4][4] = {};

    const short* gA[4];
    const short* gB[4];
#pragma unroll
    for (int g = 0; g < 4; g++)
        gA[g] = A  + (size_t)(m0 + g * 32 + wave * 8 + lrow) * K + swz;
#pragma unroll
    for (int h = 0; h < 4; h++)
        gB[h] = Bw + (size_t)(n0 + h * 32 + wave * 8 + lrow) * K + swz;

    auto stage = [&](int b, int k0) {
#pragma unroll
        for (int g = 0; g < 4; g++)
            __builtin_amdgcn_global_load_lds(GCAST(gA[g] + k0), LCAST(&As[b][(g * 32 + wave * 8) * 64]), 16, 0, 0);
#pragma unroll
        for (int h = 0; h < 4; h++)
            __builtin_amdgcn_global_load_lds(GCAST(gB[h] + k0), LCAST(&Bs[b][(h * 32 + wave * 8) * 64]), 16, 0, 0);
    };

    const int nt = K >> 6;
    stage(0, 0);
    __syncthreads();
    for (int t = 0; t < nt; ++t) {
        const int cur = t & 1;
        if (t + 1 < nt) stage(cur ^ 1, (t + 1) << 6);
        shortx8 af[2][4], bw[2][4];
#pragma unroll
        for (int ks = 0; ks < 2; ks++) {
#pragma unroll
            for (int i = 0; i < 4; i++) af[ks][i] = read8(As[cur], wr + i * 16 + lm, ks * 32 + q * 8);
#pragma unroll
            for (int j = 0; j < 4; j++) bw[ks][j] = read8(Bs[cur], wc + j * 16 + lm, ks * 32 + q * 8);
        }
#pragma unroll
        for (int ks = 0; ks < 2; ks++)
#pragma unroll
            for (int i = 0; i < 4; i++)
#pragma unroll
                for (int j = 0; j < 4; j++)
                    acc[i][j] = __builtin_amdgcn_mfma_f32_16x16x32_bf16(af[ks][i], bw[ks][j], acc[i][j], 0, 0, 0);
        __syncthreads();
    }

    const int bIdx = m0 >> 11;                    // batch (tile never straddles 2048)
    const int bh0  = bIdx * H_;
#pragma unroll
    for (int i = 0; i < 4; i++) {
        int s0 = (m0 & (S_ - 1)) + wr + i * 16 + q * 4;
#pragma unroll
        for (int j = 0; j < 4; j++) {
            int col = n0 + wc + j * 16 + lm;
            float bv = (col < PROJ) ? bias[col] : 0.f;
            float vals[4];
#pragma unroll
            for (int r = 0; r < 4; r++) vals[r] = acc[i][j][r] + bv;
            if (col < 512) {                       // v -> vT[bh][v][s]
                int h = col >> 6, vd = col & 63;
                short tmp[4];
#pragma unroll
                for (int r = 0; r < 4; r++) tmp[r] = f2bf(vals[r]);
                *(shortx4*)&vTb[((size_t)(bh0 + h) * 64 + vd) * S_ + s0] = *(shortx4*)tmp;
            } else if (col < 1024) {               // q -> q[bh][s][d]
                int h = (col >> 6) - 8, d = col & 63;
                size_t rb = ((size_t)(bh0 + h) * S_ + s0) * 64 + d;
#pragma unroll
                for (int r = 0; r < 4; r++) qb[rb + (size_t)r * 64] = f2bf(vals[r]);
            } else if (col < 1536) {               // k -> k[bh][t][d] and kT[bh][d][t]
                int h = (col >> 6) - 16, d = col & 63;
                size_t rb = ((size_t)(bh0 + h) * S_ + s0) * 64 + d;
                short tmp[4];
#pragma unroll
                for (int r = 0; r < 4; r++) { tmp[r] = f2bf(vals[r]); kb[rb + (size_t)r * 64] = tmp[r]; }
                *(shortx4*)&kTb[((size_t)(bh0 + h) * 64 + d) * S_ + s0] = *(shortx4*)tmp;
            } else if (col < PROJ) {               // n -> gate[bh][s]
                int h = col - 1536;
                float g[4];
#pragma unroll
                for (int r = 0; r < 4; r++) g[r] = __expf(-__expf(vals[r]));
                *(float4*)&gateb[(size_t)(bh0 + h) * S_ + s0] = make_float4(g[0], g[1], g[2], g[3]);
            }
        }
    }
}

// ---------------------------------------------------------------------------
// Per-chunk state via MFMA: U[v][d] = sum_{s in chunk} V[s][v] * K[s][d]
// ---------------------------------------------------------------------------
__global__ __launch_bounds__(256) void chunk_kv_mfma(const short* __restrict__ vTb,
                                                     const short* __restrict__ kTb,
                                                     float* __restrict__ kvbuf) {
    __shared__ __align__(16) short VT[64 * 64];
    __shared__ __align__(16) short KT[64 * 64];
    const int blk = blockIdx.x;
    const int c = blk & (NC - 1), bh = blk >> 5;
    const int base = c * CHK;
    const int tid = threadIdx.x, wave = tid >> 6, lane = tid & 63;
    const int lrow = lane >> 3, lgrp = lane & 7;

#pragma unroll
    for (int half = 0; half < 2; half++) {
        int v0 = wave * 8 + half * 32;
        int row = v0 + lrow;
        int gcol = ((lgrp ^ (row & 7)) << 3);
        __builtin_amdgcn_global_load_lds(GCAST(vTb + ((size_t)(bh * 64 + row)) * S_ + base + gcol),
                                         LCAST(&VT[v0 * 64]), 16, 0, 0);
        __builtin_amdgcn_global_load_lds(GCAST(kTb + ((size_t)(bh * 64 + row)) * S_ + base + gcol),
                                         LCAST(&KT[v0 * 64]), 16, 0, 0);
    }
    __syncthreads();

    const int lm = lane & 15, q = lane >> 4;
    const int wr = (wave >> 1) * 32, wc = (wave & 1) * 32;
    floatx4 acc[2][2] = {};
#pragma unroll
    for (int ks = 0; ks < 2; ks++) {
        shortx8 a[2], b2[2];
#pragma unroll
        for (int i = 0; i < 2; i++) a[i]  = read8(VT, wr + i * 16 + lm, ks * 32 + q * 8);
#pragma unroll
        for (int j = 0; j < 2; j++) b2[j] = read8(KT, wc + j * 16 + lm, ks * 32 + q * 8);
#pragma unroll
        for (int i = 0; i < 2; i++)
#pragma unroll
            for (int j = 0; j < 2; j++)
                acc[i][j] = __builtin_amdgcn_mfma_f32_16x16x32_bf16(a[i], b2[j], acc[i][j], 0, 0, 0);
    }
    float* outp = kvbuf + ((size_t)blk << 12);
#pragma unroll
    for (int i = 0; i < 2; i++)
#pragma unroll
        for (int j = 0; j < 2; j++)
#pragma unroll
            for (int r = 0; r < 4; r++)
                outp[(wr + i * 16 + q * 4 + r) * 64 + wc + j * 16 + lm] = acc[i][j][r];
}

// ---------------------------------------------------------------------------
// Group-of-4 exclusive prefix over chunk states:
// kvg[bh][g][e] = sum_{c < 4g} U[c][e],  g = 0..7.
// grid = 16 bh x 16 segs = 256 blocks.
// ---------------------------------------------------------------------------
__global__ __launch_bounds__(256) void scan_groups(const float* __restrict__ kvbuf,
                                                   float* __restrict__ kvg) {
    const int blk = blockIdx.x;
    const int bh = blk >> 4, seg = blk & 15;
    const int e = seg * 256 + threadIdx.x;
    const float* src = kvbuf + (((size_t)bh * NC) << 12) + e;
    float* dst = kvg + (((size_t)bh * 8) << 12) + e;
    float run = 0.f;
#pragma unroll
    for (int g = 0; g < 8; g++) {
        dst[(size_t)g << 12] = run;
#pragma unroll
        for (int cc = 0; cc < 4; cc++)
            run += src[(size_t)(g * 4 + cc) << 12];
    }
}

// ---------------------------------------------------------------------------
// MFMA attention chunk. Prefix = kvg[c>>2] + <=3 chunk states (fp32).
// ---------------------------------------------------------------------------
__global__ __launch_bounds__(256) void attn_mfma(const short* __restrict__ qb,
                                                 const short* __restrict__ kb,
                                                 const short* __restrict__ vTb,
                                                 const float* __restrict__ gateb,
                                                 const float* __restrict__ kvbuf,
                                                 const float* __restrict__ kvg,
                                                 short* __restrict__ ctxb) {
    __shared__ __align__(16) short Qs[64 * 64];
    __shared__ __align__(16) short Ks[64 * 64];
    __shared__ __align__(16) short VTs[64 * 64];
    __shared__ __align__(16) short Phi[64 * 64];
    __shared__ __align__(16) short Plo[64 * 64];
    __shared__ __align__(16) short Sb[64 * 72];
    __shared__ float gs[64];
    const int blk = blockIdx.x;
    const int bh = blk & (BH - 1);
    const int c  = (NC - 1) - (blk >> 4);   // heavy-prefix chunks start first
    const int base = c * CHK;
    const int tid = threadIdx.x, wave = tid >> 6, lane = tid & 63;
    const int lrow = lane >> 3, lgrp = lane & 7;

#pragma unroll
    for (int half = 0; half < 2; half++) {
        int v0 = wave * 8 + half * 32;
        int row = v0 + lrow;
        int gcol = ((lgrp ^ (row & 7)) << 3);
        __builtin_amdgcn_global_load_lds(GCAST(qb + ((size_t)bh * S_ + base + row) * 64 + gcol),
                                         LCAST(&Qs[v0 * 64]), 16, 0, 0);
        __builtin_amdgcn_global_load_lds(GCAST(kb + ((size_t)bh * S_ + base + row) * 64 + gcol),
                                         LCAST(&Ks[v0 * 64]), 16, 0, 0);
        __builtin_amdgcn_global_load_lds(GCAST(vTb + ((size_t)(bh * 64 + row)) * S_ + base + gcol),
                                         LCAST(&VTs[v0 * 64]), 16, 0, 0);
    }

    // Prefix = group prefix + <=3 preceding chunks within the group (fp32).
    float pacc[16];
    {
        const float* gp = kvg + (((size_t)bh * 8 + (c >> 2)) << 12) + tid;
#pragma unroll
        for (int it = 0; it < 16; it++) pacc[it] = gp[it * 256];
        const float* kvb = kvbuf + (((size_t)bh * NC) << 12) + tid;
        for (int cp = c & ~3; cp < c; cp++) {
            const float* p = kvb + ((size_t)cp << 12);
#pragma unroll
            for (int it = 0; it < 16; it++) pacc[it] += p[it * 256];
        }
    }
#pragma unroll
    for (int it = 0; it < 16; it++) {
        int idx = it * 256 + tid;
        int v = idx >> 6, d = idx & 63;
        float f = pacc[it];
        short hi = f2bf(f);
        short lo = f2bf(f - bf2f(hi));
        int sw = v * 64 + (((d >> 3) ^ (v & 7)) << 3) + (d & 7);
        Phi[sw] = hi; Plo[sw] = lo;
    }
    if (tid < 64) gs[tid] = gateb[(size_t)bh * S_ + base + tid];
    __syncthreads();

    const int lm = lane & 15, q = lane >> 4;
    const int wr = (wave >> 1) * 32, wc = (wave & 1) * 32;

    // Phase 1: S quadrant = Q K^T, causal mask, -> Sb bf16
    floatx4 sacc[2][2] = {};
#pragma unroll
    for (int ks = 0; ks < 2; ks++) {
        shortx8 qa[2], kf[2];
#pragma unroll
        for (int i = 0; i < 2; i++) qa[i] = read8(Qs, wr + i * 16 + lm, ks * 32 + q * 8);
#pragma unroll
        for (int j = 0; j < 2; j++) kf[j] = read8(Ks, wc + j * 16 + lm, ks * 32 + q * 8);
#pragma unroll
        for (int i = 0; i < 2; i++)
#pragma unroll
            for (int j = 0; j < 2; j++)
                sacc[i][j] = __builtin_amdgcn_mfma_f32_16x16x32_bf16(qa[i], kf[j], sacc[i][j], 0, 0, 0);
    }
#pragma unroll
    for (int i = 0; i < 2; i++)
#pragma unroll
        for (int j = 0; j < 2; j++)
#pragma unroll
            for (int r = 0; r < 4; r++) {
                int s = wr + i * 16 + q * 4 + r;
                int t = wc + j * 16 + lm;
                Sb[s * 72 + t] = f2bf(t <= s ? sacc[i][j][r] : 0.f);
            }
    __syncthreads();

    // Phase 2: O = S.V + Q.(Phi+Plo)
    floatx4 oacc[2][2] = {};
#pragma unroll
    for (int ks = 0; ks < 2; ks++) {
        shortx8 sa[2], vb[2];
#pragma unroll
        for (int i = 0; i < 2; i++)
            sa[i] = *(const shortx8*)&Sb[(wr + i * 16 + lm) * 72 + ks * 32 + q * 8];
#pragma unroll
        for (int j = 0; j < 2; j++) vb[j] = read8(VTs, wc + j * 16 + lm, ks * 32 + q * 8);
#pragma unroll
        for (int i = 0; i < 2; i++)
#pragma unroll
            for (int j = 0; j < 2; j++)
                oacc[i][j] = __builtin_amdgcn_mfma_f32_16x16x32_bf16(sa[i], vb[j], oacc[i][j], 0, 0, 0);
    }
#pragma unroll
    for (int ks = 0; ks < 2; ks++) {
        shortx8 qa[2], ph[2], pl[2];
#pragma unroll
        for (int i = 0; i < 2; i++) qa[i] = read8(Qs, wr + i * 16 + lm, ks * 32 + q * 8);
#pragma unroll
        for (int j = 0; j < 2; j++) {
            ph[j] = read8(Phi, wc + j * 16 + lm, ks * 32 + q * 8);
            pl[j] = read8(Plo, wc + j * 16 + lm, ks * 32 + q * 8);
        }
#pragma unroll
        for (int i = 0; i < 2; i++)
#pragma unroll
            for (int j = 0; j < 2; j++) {
                oacc[i][j] = __builtin_amdgcn_mfma_f32_16x16x32_bf16(qa[i], ph[j], oacc[i][j], 0, 0, 0);
                oacc[i][j] = __builtin_amdgcn_mfma_f32_16x16x32_bf16(qa[i], pl[j], oacc[i][j], 0, 0, 0);
            }
    }
    const size_t tok0 = (size_t)(bh >> 3) * S_ + base;
    const int h = bh & 7;
#pragma unroll
    for (int i = 0; i < 2; i++)
#pragma unroll
        for (int j = 0; j < 2; j++)
#pragma unroll
            for (int r = 0; r < 4; r++) {
                int s = wr + i * 16 + q * 4 + r;
                int v = wc + j * 16 + lm;
                ctxb[(tok0 + s) * DM + h * 64 + v] = f2bf(gs[s] * oacc[i][j][r]);
            }
}

// ---------------------------------------------------------------------------
extern "C" void kernel_launch(void* const* d_in, const int* in_sizes, int n_in,
                              void* d_out, int out_size, void* d_ws, size_t ws_size,
                              hipStream_t stream) {
    const float* x       = (const float*)d_in[0];
    const float* Wvqkn_w = (const float*)d_in[1];
    const float* Wvqkn_b = (const float*)d_in[2];
    const float* out_w   = (const float*)d_in[3];
    const float* out_b   = (const float*)d_in[4];
    float* out = (float*)d_out;

    float* kvbuf = (float*)d_ws;                          // 16*32*4096 f32
    float* kvg   = kvbuf + (size_t)BH * NC * 4096;        // 16*8*4096 f32
    short* xb    = (short*)(kvg + (size_t)BH * 8 * 4096);
    short* w1b   = xb   + (size_t)BS_ * DM;
    short* w2b   = w1b  + (size_t)NPAD1 * DM;
    short* ctxb  = w2b  + (size_t)DM * DM;
    short* qb    = ctxb + (size_t)BS_ * DM;
    short* kb    = qb   + (size_t)BH * S_ * 64;
    short* kTb   = kb   + (size_t)BH * S_ * 64;
    short* vTb   = kTb  + (size_t)BH * S_ * 64;
    float* gateb = (float*)(vTb + (size_t)BH * S_ * 64);

    convert_all<<<(int)((E1 + E2 + E3) / 8 / 256), 256, 0, stream>>>(
        x, Wvqkn_w, out_w, xb, w1b, w2b);

    gemm1_fused<<<dim3(NPAD1 / 128, BS_ / 128), 256, 0, stream>>>(
        xb, w1b, Wvqkn_b, qb, kb, kTb, vTb, gateb);

    chunk_kv_mfma<<<BH * NC, 256, 0, stream>>>(vTb, kTb, kvbuf);
    scan_groups<<<BH * 16, 256, 0, stream>>>(kvbuf, kvg);
    attn_mfma<<<BH * NC, 256, 0, stream>>>(qb, kb, vTb, gateb, kvbuf, kvg, ctxb);

    gemm_mfma64<<<dim3(DM / 128, BS_ / 64), 256, 0, stream>>>(ctxb, w2b, out_b, out, DM, DM);
}